// Round 5
// baseline (80.888 us; speedup 1.0000x reference)
//
#include <hip/hip_runtime.h>

// ExpertParallel dispatch+combine collapses to an exact identity permutation:
//   out[n, k, :] = x[n, :]  for k in {0, 1}
// Pure broadcast copy: read 128 MB once, write 256 MB. Traffic is minimal.
// R5: R4 (unit-stride + NT stores, 65.1 us = 5.90 TB/s) + unroll x4 for
//     deeper MLP + NT loads (x is single-use streaming). All offsets at
//     +k*stride keep every instruction perfectly coalesced.
//     TOTAL4 = 16 x (2048 blocks x 256 threads) -> 4 iterations, no tail.

constexpr int N_TOKENS = 8192;
constexpr int HIDDEN   = 4096;
constexpr int H4       = HIDDEN / 4;           // 1024 vec4 per row
constexpr int TOTAL4   = N_TOKENS * H4;        // 8,388,608 vec4

typedef float f32x4 __attribute__((ext_vector_type(4)));

__global__ __launch_bounds__(256)
void ExpertParallel_63711544868877_kernel(const f32x4* __restrict__ x4,
                                          f32x4* __restrict__ out4) {
    const int idx    = blockIdx.x * blockDim.x + threadIdx.x;
    const int stride = gridDim.x * blockDim.x;   // 524,288
    for (int i = idx; i < TOTAL4; i += 4 * stride) {
        const int i0 = i, i1 = i + stride, i2 = i + 2 * stride, i3 = i + 3 * stride;
        f32x4 v0 = __builtin_nontemporal_load(x4 + i0);
        f32x4 v1 = __builtin_nontemporal_load(x4 + i1);
        f32x4 v2 = __builtin_nontemporal_load(x4 + i2);
        f32x4 v3 = __builtin_nontemporal_load(x4 + i3);
        f32x4* o0 = out4 + ((size_t)(i0 >> 10) << 11) + (i0 & (H4 - 1));
        f32x4* o1 = out4 + ((size_t)(i1 >> 10) << 11) + (i1 & (H4 - 1));
        f32x4* o2 = out4 + ((size_t)(i2 >> 10) << 11) + (i2 & (H4 - 1));
        f32x4* o3 = out4 + ((size_t)(i3 >> 10) << 11) + (i3 & (H4 - 1));
        __builtin_nontemporal_store(v0, o0);
        __builtin_nontemporal_store(v0, o0 + H4);
        __builtin_nontemporal_store(v1, o1);
        __builtin_nontemporal_store(v1, o1 + H4);
        __builtin_nontemporal_store(v2, o2);
        __builtin_nontemporal_store(v2, o2 + H4);
        __builtin_nontemporal_store(v3, o3);
        __builtin_nontemporal_store(v3, o3 + H4);
    }
}

extern "C" void kernel_launch(void* const* d_in, const int* in_sizes, int n_in,
                              void* d_out, int out_size, void* d_ws, size_t ws_size,
                              hipStream_t stream) {
    const f32x4* x4  = (const f32x4*)d_in[0];   // x: [8192, 4096] f32
    // d_in[1] = expert_indices (unused: permutation cancels)
    // d_in[2] = ep_world_size  (unused)
    f32x4* out4 = (f32x4*)d_out;                // [8192, 2, 4096] f32

    const int block = 256;
    const int grid  = 2048;                     // stride = 524,288 vec4
    ExpertParallel_63711544868877_kernel<<<grid, block, 0, stream>>>(x4, out4);
}

// Round 6
// 64.960 us; speedup vs baseline: 1.2452x; 1.2452x over previous
//
#include <hip/hip_runtime.h>

// ExpertParallel dispatch+combine collapses to an exact identity permutation:
//   out[n, k, :] = x[n, :]  for k in {0, 1}
// Pure broadcast copy: read 128 MB once, write 256 MB. Traffic is minimal.
// R6: single-variable A/B vs R4 (65.1 us): keep cached loads + NT stores,
//     change ONLY unroll x2 -> x4. (R5's regression = NT loads or unroll x4;
//     this isolates which.) All offsets at +k*stride stay coalesced.
//     TOTAL4 = 16 x (2048 x 256) -> 4 iterations, no tail.

constexpr int N_TOKENS = 8192;
constexpr int HIDDEN   = 4096;
constexpr int H4       = HIDDEN / 4;           // 1024 vec4 per row
constexpr int TOTAL4   = N_TOKENS * H4;        // 8,388,608 vec4

typedef float f32x4 __attribute__((ext_vector_type(4)));

__global__ __launch_bounds__(256)
void ExpertParallel_63711544868877_kernel(const f32x4* __restrict__ x4,
                                          f32x4* __restrict__ out4) {
    const int idx    = blockIdx.x * blockDim.x + threadIdx.x;
    const int stride = gridDim.x * blockDim.x;   // 524,288
    for (int i = idx; i < TOTAL4; i += 4 * stride) {
        const int i0 = i, i1 = i + stride, i2 = i + 2 * stride, i3 = i + 3 * stride;
        f32x4 v0 = x4[i0];                       // cached loads (as in R4)
        f32x4 v1 = x4[i1];
        f32x4 v2 = x4[i2];
        f32x4 v3 = x4[i3];
        f32x4* o0 = out4 + ((size_t)(i0 >> 10) << 11) + (i0 & (H4 - 1));
        f32x4* o1 = out4 + ((size_t)(i1 >> 10) << 11) + (i1 & (H4 - 1));
        f32x4* o2 = out4 + ((size_t)(i2 >> 10) << 11) + (i2 & (H4 - 1));
        f32x4* o3 = out4 + ((size_t)(i3 >> 10) << 11) + (i3 & (H4 - 1));
        __builtin_nontemporal_store(v0, o0);
        __builtin_nontemporal_store(v0, o0 + H4);
        __builtin_nontemporal_store(v1, o1);
        __builtin_nontemporal_store(v1, o1 + H4);
        __builtin_nontemporal_store(v2, o2);
        __builtin_nontemporal_store(v2, o2 + H4);
        __builtin_nontemporal_store(v3, o3);
        __builtin_nontemporal_store(v3, o3 + H4);
    }
}

extern "C" void kernel_launch(void* const* d_in, const int* in_sizes, int n_in,
                              void* d_out, int out_size, void* d_ws, size_t ws_size,
                              hipStream_t stream) {
    const f32x4* x4  = (const f32x4*)d_in[0];   // x: [8192, 4096] f32
    // d_in[1] = expert_indices (unused: permutation cancels)
    // d_in[2] = ep_world_size  (unused)
    f32x4* out4 = (f32x4*)d_out;                // [8192, 2, 4096] f32

    const int block = 256;
    const int grid  = 2048;                     // stride = 524,288 vec4
    ExpertParallel_63711544868877_kernel<<<grid, block, 0, stream>>>(x4, out4);
}